// Round 10
// baseline (198.274 us; speedup 1.0000x reference)
//
#include <hip/hip_runtime.h>

// Problem constants
#define N_NODES 25000
#define N_EDGES 200000
// MUL=16, NUM_RADIAL=8, HIDDEN=64, WNUMEL=1024
// PATH_ALPHA=1/sqrt(32), INV_SQRT3=1/sqrt(3), scales folded into B-fragments.

constexpr int ET = 32;        // edges per tile
constexpr int NTILES = 6250;  // 200000/32
constexpr int GRID = 512;     // persistent grid: 2 blocks/CU resident
constexpr int XPS = 584;      // xch plane stride in floats (584%32==8 -> bank-spread planes)
constexpr int XRS = 18;       // xch row stride (2-way-free writes)
constexpr int CTS = 36;       // transposed coef row stride in floats (16B-aligned rows)
constexpr int DEGCAP = 48;    // bucket capacity per node (Poisson(8): P(deg>48)~0)

typedef __attribute__((ext_vector_type(8))) _Float16 half8;  // 8 f16 (4 VGPR)
typedef __attribute__((ext_vector_type(4))) _Float16 half4;  // 4 f16 (8B)
typedef __attribute__((ext_vector_type(4))) float float4v;   // 4 fp32

// Async global->LDS (no dest VGPRs; global addr is per-lane, LDS dest = base + lane*size).
__device__ __forceinline__ void gl_lds16(const void* g, void* l) {
    __builtin_amdgcn_global_load_lds((const __attribute__((address_space(1))) void*)g,
                                     (__attribute__((address_space(3))) void*)l, 16, 0, 0);
}
__device__ __forceinline__ void gl_lds4(const void* g, void* l) {
    __builtin_amdgcn_global_load_lds((const __attribute__((address_space(1))) void*)g,
                                     (__attribute__((address_space(3))) void*)l, 4, 0, 0);
}

// LDS-visibility-only barrier: waits own LDS ops (lgkmcnt) then syncs. Does NOT
// drain vmcnt -> in-flight stores/atomics and global_load_lds stages keep flying.
__device__ __forceinline__ void wg_barrier() {
    asm volatile("s_waitcnt lgkmcnt(0)" ::: "memory");
    __builtin_amdgcn_s_barrier();
    asm volatile("" ::: "memory");
}

// ---------------- bucket CSR-free scatter: cnt + bucket lists ----------------
__global__ __launch_bounds__(256) void k_zero(int* __restrict__ cnt) {
    const int i = blockIdx.x * 256 + threadIdx.x;
    if (i < N_NODES) cnt[i] = 0;
}

__global__ __launch_bounds__(256) void k_bucket(const int* __restrict__ edge_dst,
                                                int* __restrict__ cnt,
                                                int* __restrict__ bucket) {
    const int e = blockIdx.x * 256 + threadIdx.x;
    if (e < N_EDGES) {
        const int d = edge_dst[e];
        const int pos = atomicAdd(&cnt[d], 1);
        if (pos < DEGCAP) bucket[d * DEGCAP + pos] = e;
    }
}

// ---------------- per-node reduce + self-connection, plain stores ----------------
__global__ __launch_bounds__(256) void k_reduce(
    const float* __restrict__ x, const float* __restrict__ L0,
    const float* __restrict__ L1, const _Float16* __restrict__ ws_m,
    const int* __restrict__ cnt, const int* __restrict__ bucket,
    float* __restrict__ out) {

    __shared__ float l0[256], l1[256];
    const int t = threadIdx.x;
    l0[t] = L0[t];
    l1[t] = L1[t];
    __syncthreads();

    const int n = blockIdx.x * 4 + (t >> 6);       // 6250 blocks x 4 nodes
    const int lane = t & 63;
    const float xv = x[n * 64 + lane];

    // self-connection via wave shuffles (x row lives across the 64 lanes)
    const bool is0 = lane < 16;
    const int qq = lane - 16;
    const int v = is0 ? lane : qq / 3;
    const int k = is0 ? 0 : qq - 3 * v;
    const float* mat = is0 ? l0 : l1;
    float s = 0.f;
    #pragma unroll
    for (int u = 0; u < 16; ++u) {
        const int sel = is0 ? u : 16 + 3 * u + k;
        s = fmaf(__shfl(xv, sel), mat[u * 16 + v], s);
    }
    float acc = 0.25f * s;                         // 1/sqrt(MUL)

    // sum this node's edge messages (f16 rows, 128B each, coalesced per wave)
    const int deg = min(cnt[n], DEGCAP);
    const int* bk = bucket + n * DEGCAP;
    int i = 0;
    for (; i + 2 <= deg; i += 2) {
        const int ea = bk[i], eb = bk[i + 1];
        acc += (float)ws_m[(size_t)ea * 64 + lane] + (float)ws_m[(size_t)eb * 64 + lane];
    }
    if (i < deg) acc += (float)ws_m[(size_t)bk[i] * 64 + lane];

    out[n * 64 + lane] = acc;
}

// ---------------- edge kernel (r9 structure); TO_WS=1: f16 ws stores, no atomics ----------------
// 512 threads, 8 waves. Wave w: q = w>>1 (W2 column chunk 0..3), uh = w&1 (u-half).
// Math: au[e][v] = sum_c h[e][c] * W2[c][q*256+u*16+v]  (pure MFMA, unscaled h),
// then C[e][v] += coef[e][u] * au[e][v]  (f32 FMA, per-ROW coef: rows quad*4+r).
//   chunk 0: coef = xj0*sh0 | chunk 1: coef = b1 (INV_SQRT3 in bfr) | chunk 2: coef = xj0
//   chunk 3: coef = xj1[.,k]*sh0, k=0..2 (3 accumulator sets, ONE au evaluation)
// Schedule: segA(it): issue stage(T+2G); phase2 | B1 (lgkm-only) | phase3: MFMA+contract
// -> xch | B2 (full) | combine -> loop.
template<int TO_WS>
__global__ __launch_bounds__(512, 4) void fused_kernel(
    const float* __restrict__ x, const float* __restrict__ edge_attr,
    const float* __restrict__ edge_length, const int* __restrict__ edge_src,
    const int* __restrict__ edge_dst, const float* __restrict__ W1,
    const float* __restrict__ W2, const float* __restrict__ L0,
    const float* __restrict__ L1, float* __restrict__ out,
    _Float16* __restrict__ ws_m) {

    const int t = threadIdx.x;
    const int w = t >> 6;             // wave id 0..7
    const int lane = t & 63;
    const int q = w >> 1;             // W2 column chunk 0..3
    const int uh = w & 1;             // u-half
    const int qm = t & 15;            // MFMA m/n index
    const int quad = (t >> 4) & 3;    // lane quad within wave
    const int eL = t >> 4;            // phase2: edge within tile (0..31)
    const int uL = t & 15;            // phase2: raw u lane (0..15)
    const int uS = (uL + ((eL & 3) << 2)) & 15;   // swizzled u -> fewer xj read conflicts

    __shared__ __attribute__((aligned(16))) _Float16 lds_h16[ET * 72];   // h f16, stride 72
    __shared__ __attribute__((aligned(16))) float lds_cfT[3][16][CTS];   // coef planes 0..2, [u][e]
    __shared__ __attribute__((aligned(16))) float lds_cf3T[3][16][CTS];  // chunk3 coefs k=0..2, [u][e]
    __shared__ __attribute__((aligned(16))) float lds_xch[12 * XPS];     // term exchange
    __shared__ __attribute__((aligned(16))) float lds_w1t[64 * 8];       // W1^T [c][r]
    __shared__ __attribute__((aligned(16))) float l0[256], l1[256];      // L0, L1
    __shared__ __attribute__((aligned(16))) float lds_xj[3][ET * 64];    // 3-ring x[src], LINEAR stride 64
    __shared__ __attribute__((aligned(16))) float lds_ea[4][ET * 4];     // 4-ring edge_attr
    __shared__ __attribute__((aligned(16))) float lds_len[4][ET];        // 4-ring
    __shared__ __attribute__((aligned(16))) int   lds_dst[4][ET];        // 4-ring (atomic mode only)
    __shared__ __attribute__((aligned(16))) int   lds_srcb[4][ET];       // srcb[j%4] = src(tile j)

    // ---- persistent B fragments: W2 chunk `q`, u-half `uh`, pre-scaled f16 ----
    half8 bfr[8][2];
    {
        float scale = 0.0220970869f;                  // (1/sqrt(64)) * (1/sqrt(32))
        if (q == 1) scale *= 0.5773502692f;           // INV_SQRT3 folded
        const int kr = quad * 8;
        #pragma unroll
        for (int up = 0; up < 8; ++up) {
            const int col = q * 256 + (uh * 8 + up) * 16 + qm;
            #pragma unroll
            for (int kf = 0; kf < 2; ++kf) {
                half8 f;
                #pragma unroll
                for (int j = 0; j < 8; ++j) {
                    const int k = kf * 32 + kr + j;
                    f[j] = (_Float16)(W2[k * 1024 + col] * scale);
                }
                bfr[up][kf] = f;
            }
        }
    }
    // W1 -> LDS transposed [c][r]; L0/L1 -> LDS (atomic mode only needs l0/l1)
    lds_w1t[(t & 63) * 8 + (t >> 6)] = W1[t];
    if constexpr (!TO_WS) {
        if (t < 256) l0[t] = L0[t];
        else         l1[t - 256] = L1[t - 256];
    }

    // ---- prologue: srcb for tiles 0,1,2; stage tiles 0,1 ----
    int T = blockIdx.x;                 // tile being processed
    if (w == 0 && lane < ET) gl_lds4(edge_src + T * ET + lane, &lds_srcb[0][0]);
    if (w == 1 && lane < ET) gl_lds4(edge_src + (T + GRID) * ET + lane, &lds_srcb[1][0]);
    if (w == 2 && lane < ET) gl_lds4(edge_src + (T + 2 * GRID) * ET + lane, &lds_srcb[2][0]);
    __syncthreads();   // srcb[0..2] visible; w1t/l0/l1 visible
    {
        const int e4 = (w << 2) + (lane >> 4);
        const int c4 = (lane & 15) * 4;
        gl_lds16(x + lds_srcb[0][e4] * 64 + c4, &lds_xj[0][w * 256]);
        gl_lds16(x + lds_srcb[1][e4] * 64 + c4, &lds_xj[1][w * 256]);
    }
    if (w == 0 && lane < ET) gl_lds16(edge_attr + 4 * (T * ET + lane), &lds_ea[0][0]);
    if (w == 1 && lane < ET) gl_lds4(edge_length + T * ET + lane, &lds_len[0][0]);
    if (w == 3 && lane < ET) gl_lds16(edge_attr + 4 * ((T + GRID) * ET + lane), &lds_ea[1][0]);
    if (w == 4 && lane < ET) gl_lds4(edge_length + (T + GRID) * ET + lane, &lds_len[1][0]);
    if constexpr (!TO_WS) {
        if (w == 2 && lane < ET) gl_lds4(edge_dst + T * ET + lane, &lds_dst[0][0]);
        if (w == 5 && lane < ET) gl_lds4(edge_dst + (T + GRID) * ET + lane, &lds_dst[1][0]);
    }

    if constexpr (!TO_WS) {
        // ---- self-connection (atomic mode only): shuffle matvec + atomics ----
        const bool is0 = lane < 16;
        const int qq = lane - 16;
        const int v = is0 ? lane : qq / 3;
        const int k = is0 ? 0 : qq - 3 * v;
        const float* mat = is0 ? l0 : l1;
        for (int n = blockIdx.x * 8 + w; n < N_NODES; n += GRID * 8) {
            const float xv = x[n * 64 + lane];
            float s = 0.f;
            #pragma unroll
            for (int u = 0; u < 16; ++u) {
                const int sel = is0 ? u : 16 + 3 * u + k;
                s = fmaf(__shfl(xv, sel), mat[u * 16 + v], s);
            }
            atomicAdd(out + n * 64 + lane, 0.25f * s);   // 1/sqrt(MUL)
        }
    }
    __syncthreads();   // drains prologue stage: slots 0,1 ready

    int p = 0;   // xj ring index (it % 3)
    int m = 0;   // meta ring index (it % 4)
    while (true) {
        // ---- segA head: issue stage(T+2G) + srcb(T+3G) (zero registers held) ----
        const int T2 = T + 2 * GRID;
        if (T2 < NTILES) {
            const int p2 = (p < 1) ? p + 2 : p - 1;   // (p+2)%3
            const int m2 = (m + 2) & 3;
            {
                const int e4 = (w << 2) + (lane >> 4);
                const int src = lds_srcb[m2][e4];     // src(tile it+2), staged 1 iter ago
                gl_lds16(x + src * 64 + (lane & 15) * 4, &lds_xj[p2][w * 256]);
            }
            if (w == 0 && lane < ET) gl_lds16(edge_attr + 4 * (T2 * ET + lane), &lds_ea[m2][0]);
            if (w == 1 && lane < ET) gl_lds4(edge_length + T2 * ET + lane, &lds_len[m2][0]);
            if constexpr (!TO_WS) {
                if (w == 2 && lane < ET) gl_lds4(edge_dst + T2 * ET + lane, &lds_dst[m2][0]);
            }
            if (w == 3 && lane < ET) {
                const int e3 = min((T + 3 * GRID) * ET + lane, N_EDGES - 1);
                gl_lds4(edge_src + e3, &lds_srcb[(m + 3) & 3][0]);
            }
        }

        // ---- phase 2: transposed coef (f32) + h16 from slot p / meta m ----
        {
            const float sh0 = lds_ea[m][eL * 4 + 0];
            const float s1x = lds_ea[m][eL * 4 + 1];
            const float s1y = lds_ea[m][eL * 4 + 2];
            const float s1z = lds_ea[m][eL * 4 + 3];
            const float* xr = &lds_xj[p][eL * 64];
            const float xj0v = xr[uS];
            const float x0 = xr[16 + 3 * uS];
            const float x1 = xr[17 + 3 * uS];
            const float x2 = xr[18 + 3 * uS];
            lds_cfT[0][uS][eL] = xj0v * sh0;
            lds_cfT[1][uS][eL] = fmaf(x0, s1x, fmaf(x1, s1y, x2 * s1z));
            lds_cfT[2][uS][eL] = xj0v;
            lds_cf3T[0][uS][eL] = x0 * sh0;
            lds_cf3T[1][uS][eL] = x1 * sh0;
            lds_cf3T[2][uS][eL] = x2 * sh0;
            // h = silu(radial @ W1 / sqrt(8)) for (e=eL, c = uS*4 .. +3), stored f16
            const int c0 = uS * 4;
            const float len = lds_len[m][eL];
            float rad[8];
            #pragma unroll
            for (int r = 0; r < 8; ++r) {
                const float d = len - 0.7142857143f * (float)r;
                rad[r] = __expf(-0.5f * d * d);
            }
            half4 hv;
            #pragma unroll
            for (int i = 0; i < 4; ++i) {
                const float4v wA = *(const float4v*)(&lds_w1t[(c0 + i) * 8]);
                const float4v wB = *(const float4v*)(&lds_w1t[(c0 + i) * 8 + 4]);
                float s = rad[0] * wA[0] + rad[1] * wA[1] + rad[2] * wA[2] + rad[3] * wA[3]
                        + rad[4] * wB[0] + rad[5] * wB[1] + rad[6] * wB[2] + rad[7] * wB[3];
                s *= 0.3535533906f;
                hv[i] = (_Float16)(s / (1.f + __expf(-s)));
            }
            *(half4*)(&lds_h16[eL * 72 + c0]) = hv;
        }

        wg_barrier();   // B1 (lgkm-only): cf/h16 visible; stores/stage keep flying

        // ---- phase 3: unscaled-h MFMA -> au; contract with per-ROW coef (mt-split) ----
        if (q < 3) {
            #pragma unroll
            for (int mt = 0; mt < 2; ++mt) {
                const half8 a0 = *(const half8*)(&lds_h16[(mt * 16 + qm) * 72 + quad * 8]);
                const half8 a1 = *(const half8*)(&lds_h16[(mt * 16 + qm) * 72 + 32 + quad * 8]);
                float4v C = (float4v){0.f, 0.f, 0.f, 0.f};
                #pragma unroll
                for (int up = 0; up < 8; ++up) {
                    const int u = uh * 8 + up;
                    float4v au = __builtin_amdgcn_mfma_f32_16x16x32_f16(
                        a0, bfr[up][0], (float4v){0.f, 0.f, 0.f, 0.f}, 0, 0, 0);
                    au = __builtin_amdgcn_mfma_f32_16x16x32_f16(a1, bfr[up][1], au, 0, 0, 0);
                    const float4v cr = *(const float4v*)(&lds_cfT[q][u][mt * 16 + quad * 4]);
                    C += au * cr;     // per-row coef (rows quad*4+r)
                }
                float* xb = &lds_xch[(q * 2 + uh) * XPS];
                #pragma unroll
                for (int r = 0; r < 4; ++r)
                    xb[(mt * 16 + quad * 4 + r) * XRS + qm] = C[r];
            }
        } else {
            #pragma unroll
            for (int mt = 0; mt < 2; ++mt) {
                const half8 a0 = *(const half8*)(&lds_h16[(mt * 16 + qm) * 72 + quad * 8]);
                const half8 a1 = *(const half8*)(&lds_h16[(mt * 16 + qm) * 72 + 32 + quad * 8]);
                float4v C3[3];
                C3[0] = (float4v){0.f, 0.f, 0.f, 0.f};
                C3[1] = (float4v){0.f, 0.f, 0.f, 0.f};
                C3[2] = (float4v){0.f, 0.f, 0.f, 0.f};
                #pragma unroll
                for (int up = 0; up < 8; ++up) {
                    const int u = uh * 8 + up;
                    float4v au = __builtin_amdgcn_mfma_f32_16x16x32_f16(
                        a0, bfr[up][0], (float4v){0.f, 0.f, 0.f, 0.f}, 0, 0, 0);
                    au = __builtin_amdgcn_mfma_f32_16x16x32_f16(a1, bfr[up][1], au, 0, 0, 0);
                    #pragma unroll
                    for (int k = 0; k < 3; ++k) {
                        const float4v ck = *(const float4v*)(&lds_cf3T[k][u][mt * 16 + quad * 4]);
                        C3[k] += au * ck;
                    }
                }
                #pragma unroll
                for (int k = 0; k < 3; ++k) {
                    float* xb = &lds_xch[(6 + uh * 3 + k) * XPS];
                    #pragma unroll
                    for (int r = 0; r < 4; ++r)
                        xb[(mt * 16 + quad * 4 + r) * XRS + qm] = C3[k][r];
                }
            }
        }

        __syncthreads();   // B2: xch visible; stage(T+2G) + prev stores drained

        // ---- combine ----
        if constexpr (TO_WS) {
            // one f16x4 (8B) coalesced store per thread: e = t>>4, j0 = (t&15)*4
            const int e = t >> 4;
            const int j0 = (t & 15) * 4;
            half4 hv4;
            if (j0 < 16) {
                #pragma unroll
                for (int jj = 0; jj < 4; ++jj) {
                    const int j = j0 + jj;
                    hv4[jj] = (_Float16)(
                        (lds_xch[0 * XPS + e * XRS + j] + lds_xch[1 * XPS + e * XRS + j])
                      + (lds_xch[2 * XPS + e * XRS + j] + lds_xch[3 * XPS + e * XRS + j]));
                }
            } else {
                #pragma unroll
                for (int jj = 0; jj < 4; ++jj) {
                    const int j = j0 + jj;
                    const int qj = j - 16, v = qj / 3, k = qj - 3 * v;
                    const float s2 = lds_xch[4 * XPS + e * XRS + v]
                                   + lds_xch[5 * XPS + e * XRS + v];
                    const float s3 = lds_xch[(6 + k) * XPS + e * XRS + v]
                                   + lds_xch[(9 + k) * XPS + e * XRS + v];
                    hv4[jj] = (_Float16)fmaf(s2, lds_ea[m][e * 4 + 1 + k], s3);
                }
            }
            *(half4*)(ws_m + (size_t)(T * ET + e) * 64 + j0) = hv4;
        } else {
            // 4 output elems per thread, ONE atomic each
            #pragma unroll
            for (int i = 0; i < 4; ++i) {
                const int idx = t + 512 * i;          // 2048 = 32 edges x 64 elems
                const int e = idx >> 6, j = idx & 63;
                float val;
                if (j < 16) {
                    val = (lds_xch[0 * XPS + e * XRS + j] + lds_xch[1 * XPS + e * XRS + j])
                        + (lds_xch[2 * XPS + e * XRS + j] + lds_xch[3 * XPS + e * XRS + j]);
                } else {
                    const int qj = j - 16, v = qj / 3, k = qj - 3 * v;
                    const float s2 = lds_xch[4 * XPS + e * XRS + v]
                                   + lds_xch[5 * XPS + e * XRS + v];
                    const float s3 = lds_xch[(6 + k) * XPS + e * XRS + v]
                                   + lds_xch[(9 + k) * XPS + e * XRS + v];
                    val = fmaf(s2, lds_ea[m][e * 4 + 1 + k], s3);
                }
                atomicAdd(out + lds_dst[m][e] * 64 + j, val);
            }
        }

        T += GRID;
        if (T >= NTILES) break;
        p = (p < 2) ? p + 1 : 0;
        m = (m + 1) & 3;
    }
}

extern "C" void kernel_launch(void* const* d_in, const int* in_sizes, int n_in,
                              void* d_out, int out_size, void* d_ws, size_t ws_size,
                              hipStream_t stream) {
    const float* x           = (const float*)d_in[0];
    const float* edge_attr   = (const float*)d_in[1];
    const float* edge_length = (const float*)d_in[2];
    const int*   edge_src    = (const int*)d_in[3];
    const int*   edge_dst    = (const int*)d_in[4];
    const float* W1          = (const float*)d_in[5];
    const float* W2          = (const float*)d_in[6];
    const float* L0          = (const float*)d_in[7];
    const float* L1          = (const float*)d_in[8];
    float* out = (float*)d_out;

    const size_t WSM = (size_t)N_EDGES * 64;            // f16 elements
    const size_t need = WSM * 2 + (size_t)N_NODES * 4 + (size_t)N_NODES * DEGCAP * 4 + 256;

    if (ws_size >= need) {
        _Float16* ws_m = (_Float16*)d_ws;
        int* cnt    = (int*)((char*)d_ws + WSM * 2);
        int* bucket = cnt + N_NODES;

        k_zero<<<(N_NODES + 255) / 256, 256, 0, stream>>>(cnt);
        k_bucket<<<(N_EDGES + 255) / 256, 256, 0, stream>>>(edge_dst, cnt, bucket);
        fused_kernel<1><<<GRID, 512, 0, stream>>>(
            x, edge_attr, edge_length, edge_src, edge_dst, W1, W2, L0, L1, out, ws_m);
        k_reduce<<<N_NODES / 4, 256, 0, stream>>>(x, L0, L1, ws_m, cnt, bucket, out);
    } else {
        // fallback: round-9 atomic path
        hipMemsetAsync(out, 0, (size_t)N_NODES * 64 * sizeof(float), stream);
        fused_kernel<0><<<GRID, 512, 0, stream>>>(
            x, edge_attr, edge_length, edge_src, edge_dst, W1, W2, L0, L1, out, nullptr);
    }
}

// Round 11
// 191.259 us; speedup vs baseline: 1.0367x; 1.0367x over previous
//
#include <hip/hip_runtime.h>

// Problem constants
#define N_NODES 25000
#define N_EDGES 200000
// MUL=16, NUM_RADIAL=8, HIDDEN=64, WNUMEL=1024
// PATH_ALPHA=1/sqrt(32), INV_SQRT3=1/sqrt(3), scales folded into B-fragments.

constexpr int ET = 32;        // edges per tile
constexpr int NTILES = 6250;  // 200000/32
constexpr int GRID = 512;     // persistent grid: 2 blocks/CU resident
constexpr int XPS = 584;      // xch plane stride in floats (584%32==8 -> bank-spread planes)
constexpr int XRS = 18;       // xch row stride (2-way-free writes)
constexpr int CTS = 36;       // transposed coef row stride in floats (16B-aligned rows)

typedef __attribute__((ext_vector_type(8))) _Float16 half8;  // 8 f16 (4 VGPR)
typedef __attribute__((ext_vector_type(4))) _Float16 half4;  // 4 f16 (8B)
typedef __attribute__((ext_vector_type(4))) float float4v;   // 4 fp32

// Async global->LDS (no dest VGPRs; global addr is per-lane, LDS dest = base + lane*size).
__device__ __forceinline__ void gl_lds16(const void* g, void* l) {
    __builtin_amdgcn_global_load_lds((const __attribute__((address_space(1))) void*)g,
                                     (__attribute__((address_space(3))) void*)l, 16, 0, 0);
}
__device__ __forceinline__ void gl_lds4(const void* g, void* l) {
    __builtin_amdgcn_global_load_lds((const __attribute__((address_space(1))) void*)g,
                                     (__attribute__((address_space(3))) void*)l, 4, 0, 0);
}

// LDS-visibility-only barrier: waits own LDS ops (lgkmcnt) then syncs. Does NOT
// drain vmcnt -> in-flight atomics and global_load_lds stages keep flying.
__device__ __forceinline__ void wg_barrier() {
    asm volatile("s_waitcnt lgkmcnt(0)" ::: "memory");
    __builtin_amdgcn_s_barrier();
    asm volatile("" ::: "memory");
}

// ---------------- fused kernel: sc + edge messages, atomics into zeroed out ----------------
// 512 threads, 8 waves. Wave w: q = w>>1 (W2 column chunk 0..3), uh = w&1 (u-half).
// Math: au[e][v] = sum_c h[e][c] * W2[c][q*256+u*16+v]  (pure MFMA, unscaled h),
// then C[e][v] += coef[e][u] * au[e][v]  (f32 FMA, per-ROW coef: rows quad*4+r).
//   chunk 0: coef = xj0*sh0 | chunk 1: coef = b1 (INV_SQRT3 in bfr) | chunk 2: coef = xj0
//   chunk 3: coef = xj1[.,k]*sh0, k=0..2 (3 accumulator sets, ONE au evaluation)
// Round 11: W1 in LDS r-major [8][68] (old [c][r] was a 16-way bank conflict: bank
// (8i+j)%32 independent of lane's c) + radial exp factorized rad[r]=A*B^r*K[r]
// (8 exps -> 2). Schedule/body otherwise identical to round 9.
__global__ __launch_bounds__(512, 4) void fused_kernel(
    const float* __restrict__ x, const float* __restrict__ edge_attr,
    const float* __restrict__ edge_length, const int* __restrict__ edge_src,
    const int* __restrict__ edge_dst, const float* __restrict__ W1,
    const float* __restrict__ W2, const float* __restrict__ L0,
    const float* __restrict__ L1, float* __restrict__ out) {

    const int t = threadIdx.x;
    const int w = t >> 6;             // wave id 0..7
    const int lane = t & 63;
    const int q = w >> 1;             // W2 column chunk 0..3
    const int uh = w & 1;             // u-half
    const int qm = t & 15;            // MFMA m/n index
    const int quad = (t >> 4) & 3;    // lane quad within wave
    const int eL = t >> 4;            // phase2: edge within tile (0..31)
    const int uL = t & 15;            // phase2: raw u lane (0..15)
    const int uS = (uL + ((eL & 3) << 2)) & 15;   // swizzled u -> conflict-free xj reads

    __shared__ __attribute__((aligned(16))) _Float16 lds_h16[ET * 72];   // h f16, stride 72
    __shared__ __attribute__((aligned(16))) float lds_cfT[3][16][CTS];   // coef planes 0..2, [u][e]
    __shared__ __attribute__((aligned(16))) float lds_cf3T[3][16][CTS];  // chunk3 coefs k=0..2, [u][e]
    __shared__ __attribute__((aligned(16))) float lds_xch[12 * XPS];     // term exchange
    __shared__ __attribute__((aligned(16))) float lds_w1t[8 * 68];       // W1 r-major [r][c], pad 68
    __shared__ __attribute__((aligned(16))) float l0[256], l1[256];      // L0, L1
    __shared__ __attribute__((aligned(16))) float lds_xj[3][ET * 64];    // 3-ring x[src], LINEAR stride 64
    __shared__ __attribute__((aligned(16))) float lds_ea[4][ET * 4];     // 4-ring edge_attr
    __shared__ __attribute__((aligned(16))) float lds_len[4][ET];        // 4-ring
    __shared__ __attribute__((aligned(16))) int   lds_dst[4][ET];        // 4-ring
    __shared__ __attribute__((aligned(16))) int   lds_srcb[4][ET];       // srcb[j%4] = src(tile j)

    // ---- persistent B fragments: W2 chunk `q`, u-half `uh`, pre-scaled f16 ----
    half8 bfr[8][2];
    {
        float scale = 0.0220970869f;                  // (1/sqrt(64)) * (1/sqrt(32))
        if (q == 1) scale *= 0.5773502692f;           // INV_SQRT3 folded
        const int kr = quad * 8;
        #pragma unroll
        for (int up = 0; up < 8; ++up) {
            const int col = q * 256 + (uh * 8 + up) * 16 + qm;
            #pragma unroll
            for (int kf = 0; kf < 2; ++kf) {
                half8 f;
                #pragma unroll
                for (int j = 0; j < 8; ++j) {
                    const int k = kf * 32 + kr + j;
                    f[j] = (_Float16)(W2[k * 1024 + col] * scale);
                }
                bfr[up][kf] = f;
            }
        }
    }
    // W1 -> LDS r-major [r][c] (bank = (4r+c)%32: conflict-free store, uS-spread reads)
    lds_w1t[(t >> 6) * 68 + (t & 63)] = W1[t];
    if (t < 256) l0[t] = L0[t];
    else         l1[t - 256] = L1[t - 256];

    // ---- prologue: srcb for tiles 0,1,2; stage tiles 0,1 ----
    int T = blockIdx.x;                 // tile being processed
    // tiles T, T+GRID, T+2*GRID all < 6250 for T < 512.
    if (w == 0 && lane < ET) gl_lds4(edge_src + T * ET + lane, &lds_srcb[0][0]);
    if (w == 1 && lane < ET) gl_lds4(edge_src + (T + GRID) * ET + lane, &lds_srcb[1][0]);
    if (w == 2 && lane < ET) gl_lds4(edge_src + (T + 2 * GRID) * ET + lane, &lds_srcb[2][0]);
    __syncthreads();   // srcb[0..2] visible; w1t/l0/l1 visible
    {
        const int e4 = (w << 2) + (lane >> 4);
        const int c4 = (lane & 15) * 4;
        gl_lds16(x + lds_srcb[0][e4] * 64 + c4, &lds_xj[0][w * 256]);
        gl_lds16(x + lds_srcb[1][e4] * 64 + c4, &lds_xj[1][w * 256]);
    }
    if (w == 0 && lane < ET) gl_lds16(edge_attr + 4 * (T * ET + lane), &lds_ea[0][0]);
    if (w == 1 && lane < ET) gl_lds4(edge_length + T * ET + lane, &lds_len[0][0]);
    if (w == 2 && lane < ET) gl_lds4(edge_dst + T * ET + lane, &lds_dst[0][0]);
    if (w == 3 && lane < ET) gl_lds16(edge_attr + 4 * ((T + GRID) * ET + lane), &lds_ea[1][0]);
    if (w == 4 && lane < ET) gl_lds4(edge_length + (T + GRID) * ET + lane, &lds_len[1][0]);
    if (w == 5 && lane < ET) gl_lds4(edge_dst + (T + GRID) * ET + lane, &lds_dst[1][0]);

    // ---- self-connection under the stage latency: shuffle matvec + atomics ----
    {
        const bool is0 = lane < 16;
        const int qq = lane - 16;
        const int v = is0 ? lane : qq / 3;
        const int k = is0 ? 0 : qq - 3 * v;
        const float* mat = is0 ? l0 : l1;
        for (int n = blockIdx.x * 8 + w; n < N_NODES; n += GRID * 8) {
            const float xv = x[n * 64 + lane];
            float s = 0.f;
            #pragma unroll
            for (int u = 0; u < 16; ++u) {
                const int sel = is0 ? u : 16 + 3 * u + k;
                s = fmaf(__shfl(xv, sel), mat[u * 16 + v], s);
            }
            atomicAdd(out + n * 64 + lane, 0.25f * s);   // 1/sqrt(MUL)
        }
    }
    __syncthreads();   // drains prologue stage: slots 0,1 ready

    int p = 0;   // xj ring index (it % 3)
    int m = 0;   // meta ring index (it % 4)
    while (true) {
        // ---- segA head: issue stage(T+2G) + srcb(T+3G) (zero registers held) ----
        const int T2 = T + 2 * GRID;
        if (T2 < NTILES) {
            const int p2 = (p < 1) ? p + 2 : p - 1;   // (p+2)%3
            const int m2 = (m + 2) & 3;
            {
                const int e4 = (w << 2) + (lane >> 4);
                const int src = lds_srcb[m2][e4];     // src(tile it+2), staged 1 iter ago
                gl_lds16(x + src * 64 + (lane & 15) * 4, &lds_xj[p2][w * 256]);
            }
            if (w == 0 && lane < ET) gl_lds16(edge_attr + 4 * (T2 * ET + lane), &lds_ea[m2][0]);
            if (w == 1 && lane < ET) gl_lds4(edge_length + T2 * ET + lane, &lds_len[m2][0]);
            if (w == 2 && lane < ET) gl_lds4(edge_dst + T2 * ET + lane, &lds_dst[m2][0]);
            if (w == 3 && lane < ET) {
                const int e3 = min((T + 3 * GRID) * ET + lane, N_EDGES - 1);
                gl_lds4(edge_src + e3, &lds_srcb[(m + 3) & 3][0]);
            }
        }

        // ---- phase 2: transposed coef (f32) + h16 from slot p / meta m ----
        {
            const float sh0 = lds_ea[m][eL * 4 + 0];
            const float s1x = lds_ea[m][eL * 4 + 1];
            const float s1y = lds_ea[m][eL * 4 + 2];
            const float s1z = lds_ea[m][eL * 4 + 3];
            const float* xr = &lds_xj[p][eL * 64];
            const float xj0v = xr[uS];
            const float x0 = xr[16 + 3 * uS];
            const float x1 = xr[17 + 3 * uS];
            const float x2 = xr[18 + 3 * uS];
            lds_cfT[0][uS][eL] = xj0v * sh0;
            lds_cfT[1][uS][eL] = fmaf(x0, s1x, fmaf(x1, s1y, x2 * s1z));
            lds_cfT[2][uS][eL] = xj0v;
            lds_cf3T[0][uS][eL] = x0 * sh0;
            lds_cf3T[1][uS][eL] = x1 * sh0;
            lds_cf3T[2][uS][eL] = x2 * sh0;
            // h = silu(radial @ W1 / sqrt(8)) for (e=eL, c = uS*4 .. +3), stored f16.
            // rad[r] = exp(-0.5(len - cs*r)^2) = A * B^r * K[r],
            //   A = exp(-0.5 len^2) (1/sqrt(8) folded), B = exp(cs*len),
            //   K[r] = exp(-0.255102041 r^2) compile-time. 2 exps instead of 8.
            const int c0 = uS * 4;
            const float len = lds_len[m][eL];
            const float A = 0.3535533906f * __expf(-0.5f * len * len);
            const float B = __expf(0.7142857143f * len);
            const float B2 = B * B, B3 = B2 * B, B4 = B2 * B2;
            float rad[8];
            rad[0] = A;
            rad[1] = A * 0.7748372f * B;
            rad[2] = A * 0.3604474f * B2;
            rad[3] = A * 0.1006690f * B3;
            rad[4] = A * 0.0168800f * B4;
            rad[5] = A * 0.0016993f * (B4 * B);
            rad[6] = A * 1.027026e-4f * (B3 * B3);
            rad[7] = A * 3.7266532e-6f * (B4 * B3);
            float4v sv = (float4v){0.f, 0.f, 0.f, 0.f};
            #pragma unroll
            for (int r = 0; r < 8; ++r) {
                const float4v wr = *(const float4v*)(&lds_w1t[r * 68 + c0]);
                sv += rad[r] * wr;    // banks (4r+4uS+j)%32: 2-way max, free
            }
            half4 hv;
            #pragma unroll
            for (int i = 0; i < 4; ++i) {
                const float s = sv[i];
                hv[i] = (_Float16)(s / (1.f + __expf(-s)));
            }
            *(half4*)(&lds_h16[eL * 72 + c0]) = hv;
        }

        wg_barrier();   // B1 (lgkm-only): cf/h16 visible; atomics + stage keep flying

        // ---- phase 3: unscaled-h MFMA -> au; contract with per-ROW coef (mt-split) ----
        if (q < 3) {
            #pragma unroll
            for (int mt = 0; mt < 2; ++mt) {
                const half8 a0 = *(const half8*)(&lds_h16[(mt * 16 + qm) * 72 + quad * 8]);
                const half8 a1 = *(const half8*)(&lds_h16[(mt * 16 + qm) * 72 + 32 + quad * 8]);
                float4v C = (float4v){0.f, 0.f, 0.f, 0.f};
                #pragma unroll
                for (int up = 0; up < 8; ++up) {
                    const int u = uh * 8 + up;
                    float4v au = __builtin_amdgcn_mfma_f32_16x16x32_f16(
                        a0, bfr[up][0], (float4v){0.f, 0.f, 0.f, 0.f}, 0, 0, 0);
                    au = __builtin_amdgcn_mfma_f32_16x16x32_f16(a1, bfr[up][1], au, 0, 0, 0);
                    const float4v cr = *(const float4v*)(&lds_cfT[q][u][mt * 16 + quad * 4]);
                    C += au * cr;     // per-row coef (rows quad*4+r)
                }
                float* xb = &lds_xch[(q * 2 + uh) * XPS];
                #pragma unroll
                for (int r = 0; r < 4; ++r)
                    xb[(mt * 16 + quad * 4 + r) * XRS + qm] = C[r];
            }
        } else {
            #pragma unroll
            for (int mt = 0; mt < 2; ++mt) {
                const half8 a0 = *(const half8*)(&lds_h16[(mt * 16 + qm) * 72 + quad * 8]);
                const half8 a1 = *(const half8*)(&lds_h16[(mt * 16 + qm) * 72 + 32 + quad * 8]);
                float4v C3[3];
                C3[0] = (float4v){0.f, 0.f, 0.f, 0.f};
                C3[1] = (float4v){0.f, 0.f, 0.f, 0.f};
                C3[2] = (float4v){0.f, 0.f, 0.f, 0.f};
                #pragma unroll
                for (int up = 0; up < 8; ++up) {
                    const int u = uh * 8 + up;
                    float4v au = __builtin_amdgcn_mfma_f32_16x16x32_f16(
                        a0, bfr[up][0], (float4v){0.f, 0.f, 0.f, 0.f}, 0, 0, 0);
                    au = __builtin_amdgcn_mfma_f32_16x16x32_f16(a1, bfr[up][1], au, 0, 0, 0);
                    #pragma unroll
                    for (int k = 0; k < 3; ++k) {
                        const float4v ck = *(const float4v*)(&lds_cf3T[k][u][mt * 16 + quad * 4]);
                        C3[k] += au * ck;
                    }
                }
                #pragma unroll
                for (int k = 0; k < 3; ++k) {
                    float* xb = &lds_xch[(6 + uh * 3 + k) * XPS];
                    #pragma unroll
                    for (int r = 0; r < 4; ++r)
                        xb[(mt * 16 + quad * 4 + r) * XRS + qm] = C3[k][r];
                }
            }
        }

        __syncthreads();   // B2: xch visible; stage(T+2G) + prev atomics drained

        // ---- combine: 4 output elems per thread, ONE atomic each ----
        #pragma unroll
        for (int i = 0; i < 4; ++i) {
            const int idx = t + 512 * i;          // 2048 = 32 edges x 64 elems
            const int e = idx >> 6, j = idx & 63;
            float val;
            if (j < 16) {
                val = (lds_xch[0 * XPS + e * XRS + j] + lds_xch[1 * XPS + e * XRS + j])
                    + (lds_xch[2 * XPS + e * XRS + j] + lds_xch[3 * XPS + e * XRS + j]);
            } else {
                const int qj = j - 16, v = qj / 3, k = qj - 3 * v;
                const float s2 = lds_xch[4 * XPS + e * XRS + v] + lds_xch[5 * XPS + e * XRS + v];
                const float s3 = lds_xch[(6 + k) * XPS + e * XRS + v]
                               + lds_xch[(9 + k) * XPS + e * XRS + v];
                val = fmaf(s2, lds_ea[m][e * 4 + 1 + k], s3);
            }
            atomicAdd(out + lds_dst[m][e] * 64 + j, val);
        }

        T += GRID;
        if (T >= NTILES) break;
        p = (p < 2) ? p + 1 : 0;
        m = (m + 1) & 3;
        // next segA stages into xj[(p+2)%3] (phase2 done with it since it-1's B1)
        // and meta[(m+2)&3] (combine done with it since it-2, guaranteed by B2(it-1)).
    }
}

extern "C" void kernel_launch(void* const* d_in, const int* in_sizes, int n_in,
                              void* d_out, int out_size, void* d_ws, size_t ws_size,
                              hipStream_t stream) {
    const float* x           = (const float*)d_in[0];
    const float* edge_attr   = (const float*)d_in[1];
    const float* edge_length = (const float*)d_in[2];
    const int*   edge_src    = (const int*)d_in[3];
    const int*   edge_dst    = (const int*)d_in[4];
    const float* W1          = (const float*)d_in[5];
    const float* W2          = (const float*)d_in[6];
    const float* L0          = (const float*)d_in[7];
    const float* L1          = (const float*)d_in[8];
    float* out = (float*)d_out;

    hipMemsetAsync(out, 0, (size_t)N_NODES * 64 * sizeof(float), stream);
    fused_kernel<<<GRID, 512, 0, stream>>>(
        x, edge_attr, edge_length, edge_src, edge_dst, W1, W2, L0, L1, out);
}